// Round 1
// baseline (697.724 us; speedup 1.0000x reference)
//
#include <hip/hip_runtime.h>
#include <hip/hip_bf16.h>

#define N_NODES 100000
#define N_EDGES 800000
#define EPS 1e-5f

typedef __attribute__((ext_vector_type(8))) short short8;
typedef __attribute__((ext_vector_type(4))) float floatx4;
typedef unsigned short ushort_t;
typedef unsigned int uint_t;

__device__ __forceinline__ unsigned short f2b(float f) {
    unsigned int u = __float_as_uint(f);
    u = (u + 0x7fffu + ((u >> 16) & 1u)) >> 16;   // round-to-nearest-even
    return (unsigned short)u;
}
__device__ __forceinline__ float blo(unsigned int u) { return __uint_as_float(u << 16); }
__device__ __forceinline__ float bhi(unsigned int u) { return __uint_as_float(u & 0xffff0000u); }

// ---------------- elementwise convert fp32 -> bf16 (x input) ----------------
__global__ void cvt_f32_bf16(const float* __restrict__ x, unsigned short* __restrict__ o, int n4) {
    int i = blockIdx.x * blockDim.x + threadIdx.x;
    if (i >= n4) return;
    float4 v = ((const float4*)x)[i];
    ushort4 r;
    r.x = f2b(v.x); r.y = f2b(v.y); r.z = f2b(v.z); r.w = f2b(v.w);
    ((ushort4*)o)[i] = r;
}

// ---------------- pack [Wl;Wr] (K=256 x Hreal) into MFMA B-fragment order ----
// layout: out[(((t*NCT + c)*64 + lane)*8 + i)]  with k = t*32 + (lane>>4)*8 + i,
//         n = c*16 + (lane&15); zero-pad n >= Hreal.
__global__ void pack_w(const float* __restrict__ Wl, const float* __restrict__ Wr,
                       unsigned short* __restrict__ out, int Hreal, int NCT) {
    int tid = blockIdx.x * blockDim.x + threadIdx.x;
    int total = NCT * 8 * 64 * 8;
    if (tid >= total) return;
    int i = tid & 7;
    int lane = (tid >> 3) & 63;
    int q = tid >> 9;
    int c = q % NCT;
    int t = q / NCT;
    int k = t * 32 + (lane >> 4) * 8 + i;
    int n = c * 16 + (lane & 15);
    float v = 0.f;
    if (n < Hreal) v = (k < 128) ? Wl[k * Hreal + n] : Wr[(k - 128) * Hreal + n];
    out[tid] = f2b(v);
}

// ---------------- CSR build ----------------
__global__ void hist_k(const int* __restrict__ dst, unsigned int* __restrict__ cnt) {
    int e = blockIdx.x * blockDim.x + threadIdx.x;
    if (e < N_EDGES) atomicAdd(&cnt[dst[e]], 1u);
}

__global__ void scan1(const unsigned int* __restrict__ cnt, unsigned int* __restrict__ rowptr,
                      unsigned int* __restrict__ bsum) {
    __shared__ unsigned int sh[256];
    int t = threadIdx.x;
    int i = blockIdx.x * 256 + t;
    unsigned int v = (i < N_NODES) ? cnt[i] : 0u;
    sh[t] = v; __syncthreads();
    for (int off = 1; off < 256; off <<= 1) {
        unsigned int add = (t >= off) ? sh[t - off] : 0u;
        __syncthreads();
        sh[t] += add;
        __syncthreads();
    }
    if (i < N_NODES) rowptr[i] = sh[t] - v;  // exclusive within block
    if (t == 255) bsum[blockIdx.x] = sh[255];
}

__global__ void scan2(const unsigned int* __restrict__ bsum, unsigned int* __restrict__ boff, int nb) {
    __shared__ unsigned int sh[512];
    int t = threadIdx.x;
    unsigned int v = (t < nb) ? bsum[t] : 0u;
    sh[t] = v; __syncthreads();
    for (int off = 1; off < 512; off <<= 1) {
        unsigned int add = (t >= off) ? sh[t - off] : 0u;
        __syncthreads();
        sh[t] += add;
        __syncthreads();
    }
    if (t < nb) boff[t] = sh[t] - v;
}

__global__ void scan3(unsigned int* __restrict__ rowptr, const unsigned int* __restrict__ boff,
                      unsigned int* __restrict__ cursor) {
    int i = blockIdx.x * 256 + threadIdx.x;
    if (i < N_NODES) {
        unsigned int r = rowptr[i] + boff[blockIdx.x];
        rowptr[i] = r;
        cursor[i] = r;
    }
    if (i == N_NODES) rowptr[N_NODES] = N_EDGES;
}

__global__ void scatter_k(const int* __restrict__ src, const int* __restrict__ dst,
                          unsigned int* __restrict__ cursor, int* __restrict__ srclist) {
    int e = blockIdx.x * blockDim.x + threadIdx.x;
    if (e < N_EDGES) {
        unsigned int p = atomicAdd(&cursor[dst[e]], 1u);
        srclist[p] = src[e];
    }
}

// ---------------- mean aggregation: one wave per node, 2 feats/lane ----------
__global__ void agg_k(const unsigned short* __restrict__ h, const unsigned int* __restrict__ rowptr,
                      const int* __restrict__ srclist, unsigned short* __restrict__ mean) {
    int tid = blockIdx.x * 256 + threadIdx.x;
    int node = tid >> 6;
    int lane = tid & 63;
    if (node >= N_NODES) return;
    unsigned int b = rowptr[node], e = rowptr[node + 1];
    float s0 = 0.f, s1 = 0.f;
    const unsigned int* hp = (const unsigned int*)h;
    for (unsigned int p = b; p < e; ++p) {
        int s = srclist[p];
        unsigned int u = hp[(size_t)s * 64 + lane];
        s0 += blo(u);
        s1 += bhi(u);
    }
    unsigned int deg = e - b;
    float r = 1.0f / (float)(deg > 1u ? deg : 1u);
    unsigned int o = (unsigned int)f2b(s0 * r) | ((unsigned int)f2b(s1 * r) << 16);
    ((unsigned int*)mean)[(size_t)node * 64 + lane] = o;
}

// ---------------- GEMM: C[N x HSTORE] = [mean|h] @ packedB, bf16 MFMA --------
// block = 256 thr (4 waves); wave handles 32 rows x NCT*16 cols; K = 256.
template <int NCT, int HSTORE, bool BIAS>
__global__ void __launch_bounds__(256) gemm_k(const unsigned short* __restrict__ meanb,
                                              const unsigned short* __restrict__ hb,
                                              const unsigned short* __restrict__ Bp,
                                              const float* __restrict__ bias,
                                              float* __restrict__ out) {
    int wave = threadIdx.x >> 6;
    int lane = threadIdx.x & 63;
    int quad = lane >> 4;
    int l15 = lane & 15;
    int rowbase = blockIdx.x * 128 + wave * 32;

    floatx4 acc[2][NCT];
#pragma unroll
    for (int w = 0; w < 2; w++)
#pragma unroll
        for (int c = 0; c < NCT; c++) acc[w][c] = (floatx4){0.f, 0.f, 0.f, 0.f};

    int r0 = rowbase + l15;       if (r0 > N_NODES - 1) r0 = N_NODES - 1;
    int r1 = rowbase + 16 + l15;  if (r1 > N_NODES - 1) r1 = N_NODES - 1;

#pragma unroll
    for (int t = 0; t < 8; t++) {
        const unsigned short* base = (t < 4) ? meanb : hb;
        int koff = (t & 3) * 32 + quad * 8;
        short8 a0 = *(const short8*)(base + (size_t)r0 * 128 + koff);
        short8 a1 = *(const short8*)(base + (size_t)r1 * 128 + koff);
#pragma unroll
        for (int c = 0; c < NCT; c++) {
            short8 bf = *(const short8*)(Bp + ((size_t)(t * NCT + c) * 64 + lane) * 8);
            acc[0][c] = __builtin_amdgcn_mfma_f32_16x16x32_bf16(a0, bf, acc[0][c], 0, 0, 0);
            acc[1][c] = __builtin_amdgcn_mfma_f32_16x16x32_bf16(a1, bf, acc[1][c], 0, 0, 0);
        }
    }

#pragma unroll
    for (int w = 0; w < 2; w++) {
#pragma unroll
        for (int c = 0; c < NCT; c++) {
            int col = c * 16 + l15;
            if (NCT * 16 > HSTORE && col >= HSTORE) continue;  // layer-2 col pad guard
#pragma unroll
            for (int r = 0; r < 4; r++) {
                int row = rowbase + w * 16 + quad * 4 + r;
                if (row < N_NODES) {
                    float v = acc[w][c][r];
                    if (BIAS) v += bias[col];
                    out[(size_t)row * HSTORE + col] = v;
                }
            }
        }
    }
}

// ---------------- BN: column sums / sums-of-squares --------------------------
__global__ void bn_stats(const float* __restrict__ C, float* __restrict__ sums) {
    int t = threadIdx.x;
    int col = t & 127;
    int rh = t >> 7;
    int base = blockIdx.x * 256;
    float s = 0.f, s2 = 0.f;
    for (int r = rh; r < 256; r += 2) {
        int row = base + r;
        if (row < N_NODES) {
            float v = C[(size_t)row * 128 + col];
            s += v;
            s2 += v * v;
        }
    }
    atomicAdd(&sums[col], s);
    atomicAdd(&sums[128 + col], s2);
}

__global__ void bn_finalize(const float* __restrict__ sums, const float* __restrict__ g,
                            const float* __restrict__ be, float* __restrict__ sc,
                            float* __restrict__ sh) {
    int j = threadIdx.x;
    float inv_n = 1.0f / (float)N_NODES;
    float mu = sums[j] * inv_n;
    float var = sums[128 + j] * inv_n - mu * mu;
    float s = g[j] * rsqrtf(var + EPS);
    sc[j] = s;
    sh[j] = be[j] - mu * s;
}

__global__ void bn_apply(const float* __restrict__ C, const float* __restrict__ sc,
                         const float* __restrict__ sh, unsigned short* __restrict__ ho) {
    int i = blockIdx.x * 256 + threadIdx.x;  // one float4 per thread
    if (i >= N_NODES * 32) return;
    float4 v = ((const float4*)C)[i];
    int c0 = (i * 4) & 127;
    float a = fmaxf(0.f, v.x * sc[c0] + sh[c0]);
    float b = fmaxf(0.f, v.y * sc[c0 + 1] + sh[c0 + 1]);
    float c = fmaxf(0.f, v.z * sc[c0 + 2] + sh[c0 + 2]);
    float d = fmaxf(0.f, v.w * sc[c0 + 3] + sh[c0 + 3]);
    ushort4 o;
    o.x = f2b(a); o.y = f2b(b); o.z = f2b(c); o.w = f2b(d);
    ((ushort4*)ho)[i] = o;
}

// ---------------- host ----------------
extern "C" void kernel_launch(void* const* d_in, const int* in_sizes, int n_in,
                              void* d_out, int out_size, void* d_ws, size_t ws_size,
                              hipStream_t stream) {
    const float* x   = (const float*)d_in[0];
    const int* ei    = (const int*)d_in[1];     // [2, E] int32: row 0 = src, row 1 = dst
    const float* Wl0 = (const float*)d_in[2];
    const float* Wr0 = (const float*)d_in[3];
    const float* Wl1 = (const float*)d_in[4];
    const float* Wr1 = (const float*)d_in[5];
    const float* Wl2 = (const float*)d_in[6];
    const float* Wr2 = (const float*)d_in[7];
    const float* b2  = (const float*)d_in[8];
    const float* g0  = (const float*)d_in[9];
    const float* be0 = (const float*)d_in[10];
    const float* g1  = (const float*)d_in[11];
    const float* be1 = (const float*)d_in[12];

    char* ws = (char*)d_ws;
    size_t off = 0;
    auto alloc = [&](size_t bytes) -> void* {
        void* p = ws + off;
        off += (bytes + 4095) & ~(size_t)4095;
        return p;
    };

    const size_t NB16 = (size_t)N_NODES * 128 * 2;  // 25.6 MB bf16 feature buffer
    unsigned short* xb   = (unsigned short*)alloc(NB16);   // x in bf16; reused as h2
    unsigned short* h1   = (unsigned short*)alloc(NB16);
    unsigned short* mean = (unsigned short*)alloc(NB16);
    float* C             = (float*)alloc((size_t)N_NODES * 128 * 4);
    unsigned int* cnt    = (unsigned int*)alloc((size_t)N_NODES * 4);
    unsigned int* rowptr = (unsigned int*)alloc((size_t)(N_NODES + 1) * 4);
    unsigned int* cursor = (unsigned int*)alloc((size_t)N_NODES * 4);
    int* srclist         = (int*)alloc((size_t)N_EDGES * 4);
    unsigned int* bsum   = (unsigned int*)alloc(512 * 4);
    unsigned int* boff   = (unsigned int*)alloc(512 * 4);
    float* sums          = (float*)alloc(256 * 4);
    float* sc            = (float*)alloc(128 * 4);
    float* sh            = (float*)alloc(128 * 4);
    unsigned short* W0p  = (unsigned short*)alloc(8 * 8 * 64 * 8 * 2);
    unsigned short* W1p  = (unsigned short*)alloc(8 * 8 * 64 * 8 * 2);
    unsigned short* W2p  = (unsigned short*)alloc(3 * 8 * 64 * 8 * 2);
    unsigned short* h2   = xb;  // alias: xb dead after layer-0 GEMM

    const int* srcp = ei;
    const int* dstp = ei + N_EDGES;

    // ---- prep ----
    hipMemsetAsync(cnt, 0, (size_t)N_NODES * 4, stream);
    cvt_f32_bf16<<<12500, 256, 0, stream>>>(x, xb, N_NODES * 32);
    pack_w<<<(8 * 4096 + 255) / 256, 256, 0, stream>>>(Wl0, Wr0, W0p, 128, 8);
    pack_w<<<(8 * 4096 + 255) / 256, 256, 0, stream>>>(Wl1, Wr1, W1p, 128, 8);
    pack_w<<<(3 * 4096 + 255) / 256, 256, 0, stream>>>(Wl2, Wr2, W2p, 40, 3);

    // ---- CSR ----
    hist_k<<<(N_EDGES + 255) / 256, 256, 0, stream>>>(dstp, cnt);
    scan1<<<391, 256, 0, stream>>>(cnt, rowptr, bsum);
    scan2<<<1, 512, 0, stream>>>(bsum, boff, 391);
    scan3<<<391, 256, 0, stream>>>(rowptr, boff, cursor);
    scatter_k<<<(N_EDGES + 255) / 256, 256, 0, stream>>>(srcp, dstp, cursor, srclist);

    // ---- layer 0 ----
    agg_k<<<25000, 256, 0, stream>>>(xb, rowptr, srclist, mean);
    gemm_k<8, 128, false><<<782, 256, 0, stream>>>(mean, xb, W0p, nullptr, C);
    hipMemsetAsync(sums, 0, 256 * 4, stream);
    bn_stats<<<391, 256, 0, stream>>>(C, sums);
    bn_finalize<<<1, 128, 0, stream>>>(sums, g0, be0, sc, sh);
    bn_apply<<<12500, 256, 0, stream>>>(C, sc, sh, h1);

    // ---- layer 1 ----
    agg_k<<<25000, 256, 0, stream>>>(h1, rowptr, srclist, mean);
    gemm_k<8, 128, false><<<782, 256, 0, stream>>>(mean, h1, W1p, nullptr, C);
    hipMemsetAsync(sums, 0, 256 * 4, stream);
    bn_stats<<<391, 256, 0, stream>>>(C, sums);
    bn_finalize<<<1, 128, 0, stream>>>(sums, g1, be1, sc, sh);
    bn_apply<<<12500, 256, 0, stream>>>(C, sc, sh, h2);

    // ---- layer 2 (writes d_out, fp32 [N,40]) ----
    agg_k<<<25000, 256, 0, stream>>>(h2, rowptr, srclist, mean);
    gemm_k<3, 40, true><<<782, 256, 0, stream>>>(mean, h2, W2p, b2, (float*)d_out);

    (void)in_sizes; (void)n_in; (void)out_size; (void)ws_size;
}

// Round 2
// 585.793 us; speedup vs baseline: 1.1911x; 1.1911x over previous
//
#include <hip/hip_runtime.h>
#include <hip/hip_bf16.h>

#define N_NODES 100000
#define N_EDGES 800000
#define EPS 1e-5f

typedef __attribute__((ext_vector_type(8))) short short8;
typedef __attribute__((ext_vector_type(4))) float floatx4;

__device__ __forceinline__ unsigned short f2b(float f) {
    unsigned int u = __float_as_uint(f);
    u = (u + 0x7fffu + ((u >> 16) & 1u)) >> 16;   // round-to-nearest-even
    return (unsigned short)u;
}
__device__ __forceinline__ float blo(unsigned int u) { return __uint_as_float(u << 16); }
__device__ __forceinline__ float bhi(unsigned int u) { return __uint_as_float(u & 0xffff0000u); }

// ---------------- elementwise convert fp32 -> bf16 (x input) ----------------
__global__ void cvt_f32_bf16(const float* __restrict__ x, unsigned short* __restrict__ o, int n4) {
    int i = blockIdx.x * blockDim.x + threadIdx.x;
    if (i >= n4) return;
    float4 v = ((const float4*)x)[i];
    ushort4 r;
    r.x = f2b(v.x); r.y = f2b(v.y); r.z = f2b(v.z); r.w = f2b(v.w);
    ((ushort4*)o)[i] = r;
}

// ---------------- pack [Wl;Wr] (K=256 x Hreal) into MFMA B-fragment order ----
__global__ void pack_w(const float* __restrict__ Wl, const float* __restrict__ Wr,
                       unsigned short* __restrict__ out, int Hreal, int NCT) {
    int tid = blockIdx.x * blockDim.x + threadIdx.x;
    int total = NCT * 8 * 64 * 8;
    if (tid >= total) return;
    int i = tid & 7;
    int lane = (tid >> 3) & 63;
    int q = tid >> 9;
    int c = q % NCT;
    int t = q / NCT;
    int k = t * 32 + (lane >> 4) * 8 + i;
    int n = c * 16 + (lane & 15);
    float v = 0.f;
    if (n < Hreal) v = (k < 128) ? Wl[k * Hreal + n] : Wr[(k - 128) * Hreal + n];
    out[tid] = f2b(v);
}

// ---------------- CSR build ----------------
__global__ void hist_k(const int* __restrict__ dst, unsigned int* __restrict__ cnt) {
    int e = blockIdx.x * blockDim.x + threadIdx.x;
    if (e < N_EDGES) atomicAdd(&cnt[dst[e]], 1u);
}

__global__ void scan1(const unsigned int* __restrict__ cnt, unsigned int* __restrict__ rowptr,
                      unsigned int* __restrict__ bsum) {
    __shared__ unsigned int sh[256];
    int t = threadIdx.x;
    int i = blockIdx.x * 256 + t;
    unsigned int v = (i < N_NODES) ? cnt[i] : 0u;
    sh[t] = v; __syncthreads();
    for (int off = 1; off < 256; off <<= 1) {
        unsigned int add = (t >= off) ? sh[t - off] : 0u;
        __syncthreads();
        sh[t] += add;
        __syncthreads();
    }
    if (i < N_NODES) rowptr[i] = sh[t] - v;  // exclusive within block
    if (t == 255) bsum[blockIdx.x] = sh[255];
}

__global__ void scan2(const unsigned int* __restrict__ bsum, unsigned int* __restrict__ boff, int nb) {
    __shared__ unsigned int sh[512];
    int t = threadIdx.x;
    unsigned int v = (t < nb) ? bsum[t] : 0u;
    sh[t] = v; __syncthreads();
    for (int off = 1; off < 512; off <<= 1) {
        unsigned int add = (t >= off) ? sh[t - off] : 0u;
        __syncthreads();
        sh[t] += add;
        __syncthreads();
    }
    if (t < nb) boff[t] = sh[t] - v;
}

__global__ void scan3(unsigned int* __restrict__ rowptr, const unsigned int* __restrict__ boff,
                      unsigned int* __restrict__ cursor) {
    int i = blockIdx.x * 256 + threadIdx.x;
    if (i < N_NODES) {
        unsigned int r = rowptr[i] + boff[blockIdx.x];
        rowptr[i] = r;
        cursor[i] = r;
    }
    if (i == N_NODES) rowptr[N_NODES] = N_EDGES;
}

__global__ void scatter_k(const int* __restrict__ src, const int* __restrict__ dst,
                          unsigned int* __restrict__ cursor, int* __restrict__ srclist) {
    int e = blockIdx.x * blockDim.x + threadIdx.x;
    if (e < N_EDGES) {
        unsigned int p = atomicAdd(&cursor[dst[e]], 1u);
        srclist[p] = src[e];
    }
}

// ---------------- mean aggregation: one wave per node, unroll-4 MLP ----------
// 4 independent src-row gathers in flight per wave to break the serial
// latency chain (R1 post-mortem: 84.8 us, VALUBusy 20%, latency-bound).
__global__ void __launch_bounds__(256) agg_k(const unsigned short* __restrict__ h,
                                             const unsigned int* __restrict__ rowptr,
                                             const int* __restrict__ srclist,
                                             unsigned short* __restrict__ mean) {
    int tid = blockIdx.x * 256 + threadIdx.x;
    int node = tid >> 6;
    int lane = tid & 63;
    if (node >= N_NODES) return;
    unsigned int b = rowptr[node], e = rowptr[node + 1];
    const unsigned int* hp = (const unsigned int*)h;
    float a0 = 0.f, a1 = 0.f, b0 = 0.f, b1 = 0.f;
    float c0 = 0.f, c1 = 0.f, d0 = 0.f, d1 = 0.f;
    unsigned int p = b;
    for (; p + 4 <= e; p += 4) {
        int ia = srclist[p];
        int ib = srclist[p + 1];
        int ic = srclist[p + 2];
        int id = srclist[p + 3];
        unsigned int u0 = hp[(size_t)ia * 64 + lane];
        unsigned int u1 = hp[(size_t)ib * 64 + lane];
        unsigned int u2 = hp[(size_t)ic * 64 + lane];
        unsigned int u3 = hp[(size_t)id * 64 + lane];
        a0 += blo(u0); a1 += bhi(u0);
        b0 += blo(u1); b1 += bhi(u1);
        c0 += blo(u2); c1 += bhi(u2);
        d0 += blo(u3); d1 += bhi(u3);
    }
    for (; p < e; ++p) {
        int s = srclist[p];
        unsigned int u = hp[(size_t)s * 64 + lane];
        a0 += blo(u); a1 += bhi(u);
    }
    float s0 = (a0 + b0) + (c0 + d0);
    float s1 = (a1 + b1) + (c1 + d1);
    unsigned int deg = e - b;
    float r = 1.0f / (float)(deg > 1u ? deg : 1u);
    unsigned int o = (unsigned int)f2b(s0 * r) | ((unsigned int)f2b(s1 * r) << 16);
    ((unsigned int*)mean)[(size_t)node * 64 + lane] = o;
}

// ---------------- GEMM: C[N x HSTORE] = [mean|h] @ packedB, bf16 MFMA --------
template <int NCT, int HSTORE, bool BIAS>
__global__ void __launch_bounds__(256) gemm_k(const unsigned short* __restrict__ meanb,
                                              const unsigned short* __restrict__ hb,
                                              const unsigned short* __restrict__ Bp,
                                              const float* __restrict__ bias,
                                              float* __restrict__ out) {
    int wave = threadIdx.x >> 6;
    int lane = threadIdx.x & 63;
    int quad = lane >> 4;
    int l15 = lane & 15;
    int rowbase = blockIdx.x * 128 + wave * 32;

    floatx4 acc[2][NCT];
#pragma unroll
    for (int w = 0; w < 2; w++)
#pragma unroll
        for (int c = 0; c < NCT; c++) acc[w][c] = (floatx4){0.f, 0.f, 0.f, 0.f};

    int r0 = rowbase + l15;       if (r0 > N_NODES - 1) r0 = N_NODES - 1;
    int r1 = rowbase + 16 + l15;  if (r1 > N_NODES - 1) r1 = N_NODES - 1;

#pragma unroll
    for (int t = 0; t < 8; t++) {
        const unsigned short* base = (t < 4) ? meanb : hb;
        int koff = (t & 3) * 32 + quad * 8;
        short8 a0 = *(const short8*)(base + (size_t)r0 * 128 + koff);
        short8 a1 = *(const short8*)(base + (size_t)r1 * 128 + koff);
#pragma unroll
        for (int c = 0; c < NCT; c++) {
            short8 bf = *(const short8*)(Bp + ((size_t)(t * NCT + c) * 64 + lane) * 8);
            acc[0][c] = __builtin_amdgcn_mfma_f32_16x16x32_bf16(a0, bf, acc[0][c], 0, 0, 0);
            acc[1][c] = __builtin_amdgcn_mfma_f32_16x16x32_bf16(a1, bf, acc[1][c], 0, 0, 0);
        }
    }

#pragma unroll
    for (int w = 0; w < 2; w++) {
#pragma unroll
        for (int c = 0; c < NCT; c++) {
            int col = c * 16 + l15;
            if (NCT * 16 > HSTORE && col >= HSTORE) continue;  // layer-2 col pad guard
#pragma unroll
            for (int r = 0; r < 4; r++) {
                int row = rowbase + w * 16 + quad * 4 + r;
                if (row < N_NODES) {
                    float v = acc[w][c][r];
                    if (BIAS) v += bias[col];
                    out[(size_t)row * HSTORE + col] = v;
                }
            }
        }
    }
}

// ---------------- BN: column sums / sums-of-squares --------------------------
__global__ void bn_stats(const float* __restrict__ C, float* __restrict__ sums) {
    int t = threadIdx.x;
    int col = t & 127;
    int rh = t >> 7;
    int base = blockIdx.x * 256;
    float s = 0.f, s2 = 0.f;
    for (int r = rh; r < 256; r += 2) {
        int row = base + r;
        if (row < N_NODES) {
            float v = C[(size_t)row * 128 + col];
            s += v;
            s2 += v * v;
        }
    }
    atomicAdd(&sums[col], s);
    atomicAdd(&sums[128 + col], s2);
}

__global__ void bn_finalize(const float* __restrict__ sums, const float* __restrict__ g,
                            const float* __restrict__ be, float* __restrict__ sc,
                            float* __restrict__ sh) {
    int j = threadIdx.x;
    float inv_n = 1.0f / (float)N_NODES;
    float mu = sums[j] * inv_n;
    float var = sums[128 + j] * inv_n - mu * mu;
    float s = g[j] * rsqrtf(var + EPS);
    sc[j] = s;
    sh[j] = be[j] - mu * s;
}

__global__ void bn_apply(const float* __restrict__ C, const float* __restrict__ sc,
                         const float* __restrict__ sh, unsigned short* __restrict__ ho) {
    int i = blockIdx.x * 256 + threadIdx.x;  // one float4 per thread
    if (i >= N_NODES * 32) return;
    float4 v = ((const float4*)C)[i];
    int c0 = (i * 4) & 127;
    float a = fmaxf(0.f, v.x * sc[c0] + sh[c0]);
    float b = fmaxf(0.f, v.y * sc[c0 + 1] + sh[c0 + 1]);
    float c = fmaxf(0.f, v.z * sc[c0 + 2] + sh[c0 + 2]);
    float d = fmaxf(0.f, v.w * sc[c0 + 3] + sh[c0 + 3]);
    ushort4 o;
    o.x = f2b(a); o.y = f2b(b); o.z = f2b(c); o.w = f2b(d);
    ((ushort4*)ho)[i] = o;
}

// ---------------- host ----------------
extern "C" void kernel_launch(void* const* d_in, const int* in_sizes, int n_in,
                              void* d_out, int out_size, void* d_ws, size_t ws_size,
                              hipStream_t stream) {
    const float* x   = (const float*)d_in[0];
    const int* ei    = (const int*)d_in[1];     // [2, E] int32: row 0 = src, row 1 = dst
    const float* Wl0 = (const float*)d_in[2];
    const float* Wr0 = (const float*)d_in[3];
    const float* Wl1 = (const float*)d_in[4];
    const float* Wr1 = (const float*)d_in[5];
    const float* Wl2 = (const float*)d_in[6];
    const float* Wr2 = (const float*)d_in[7];
    const float* b2  = (const float*)d_in[8];
    const float* g0  = (const float*)d_in[9];
    const float* be0 = (const float*)d_in[10];
    const float* g1  = (const float*)d_in[11];
    const float* be1 = (const float*)d_in[12];

    char* ws = (char*)d_ws;
    size_t off = 0;
    auto alloc = [&](size_t bytes) -> void* {
        void* p = ws + off;
        off += (bytes + 4095) & ~(size_t)4095;
        return p;
    };

    const size_t NB16 = (size_t)N_NODES * 128 * 2;  // 25.6 MB bf16 feature buffer
    unsigned short* xb   = (unsigned short*)alloc(NB16);   // x in bf16; reused as h2
    unsigned short* h1   = (unsigned short*)alloc(NB16);
    unsigned short* mean = (unsigned short*)alloc(NB16);
    float* C             = (float*)alloc((size_t)N_NODES * 128 * 4);
    unsigned int* cnt    = (unsigned int*)alloc((size_t)N_NODES * 4);
    unsigned int* rowptr = (unsigned int*)alloc((size_t)(N_NODES + 1) * 4);
    unsigned int* cursor = (unsigned int*)alloc((size_t)N_NODES * 4);
    int* srclist         = (int*)alloc((size_t)N_EDGES * 4);
    unsigned int* bsum   = (unsigned int*)alloc(512 * 4);
    unsigned int* boff   = (unsigned int*)alloc(512 * 4);
    float* sums          = (float*)alloc(256 * 4);
    float* sc            = (float*)alloc(128 * 4);
    float* sh            = (float*)alloc(128 * 4);
    unsigned short* W0p  = (unsigned short*)alloc(8 * 8 * 64 * 8 * 2);
    unsigned short* W1p  = (unsigned short*)alloc(8 * 8 * 64 * 8 * 2);
    unsigned short* W2p  = (unsigned short*)alloc(3 * 8 * 64 * 8 * 2);
    unsigned short* h2   = xb;  // alias: xb dead after layer-0 GEMM

    const int* srcp = ei;
    const int* dstp = ei + N_EDGES;

    // ---- prep ----
    hipMemsetAsync(cnt, 0, (size_t)N_NODES * 4, stream);
    cvt_f32_bf16<<<12500, 256, 0, stream>>>(x, xb, N_NODES * 32);
    pack_w<<<(8 * 4096 + 255) / 256, 256, 0, stream>>>(Wl0, Wr0, W0p, 128, 8);
    pack_w<<<(8 * 4096 + 255) / 256, 256, 0, stream>>>(Wl1, Wr1, W1p, 128, 8);
    pack_w<<<(3 * 4096 + 255) / 256, 256, 0, stream>>>(Wl2, Wr2, W2p, 40, 3);

    // ---- CSR ----
    hist_k<<<(N_EDGES + 255) / 256, 256, 0, stream>>>(dstp, cnt);
    scan1<<<391, 256, 0, stream>>>(cnt, rowptr, bsum);
    scan2<<<1, 512, 0, stream>>>(bsum, boff, 391);
    scan3<<<391, 256, 0, stream>>>(rowptr, boff, cursor);
    scatter_k<<<(N_EDGES + 255) / 256, 256, 0, stream>>>(srcp, dstp, cursor, srclist);

    // ---- layer 0 ----
    agg_k<<<25000, 256, 0, stream>>>(xb, rowptr, srclist, mean);
    gemm_k<8, 128, false><<<782, 256, 0, stream>>>(mean, xb, W0p, nullptr, C);
    hipMemsetAsync(sums, 0, 256 * 4, stream);
    bn_stats<<<391, 256, 0, stream>>>(C, sums);
    bn_finalize<<<1, 128, 0, stream>>>(sums, g0, be0, sc, sh);
    bn_apply<<<12500, 256, 0, stream>>>(C, sc, sh, h1);

    // ---- layer 1 ----
    agg_k<<<25000, 256, 0, stream>>>(h1, rowptr, srclist, mean);
    gemm_k<8, 128, false><<<782, 256, 0, stream>>>(mean, h1, W1p, nullptr, C);
    hipMemsetAsync(sums, 0, 256 * 4, stream);
    bn_stats<<<391, 256, 0, stream>>>(C, sums);
    bn_finalize<<<1, 128, 0, stream>>>(sums, g1, be1, sc, sh);
    bn_apply<<<12500, 256, 0, stream>>>(C, sc, sh, h2);

    // ---- layer 2 (writes d_out, fp32 [N,40]) ----
    agg_k<<<25000, 256, 0, stream>>>(h2, rowptr, srclist, mean);
    gemm_k<3, 40, true><<<782, 256, 0, stream>>>(mean, h2, W2p, b2, (float*)d_out);

    (void)in_sizes; (void)n_in; (void)out_size; (void)ws_size;
}